// Round 1
// baseline (50.485 us; speedup 1.0000x reference)
//
#include <hip/hip_runtime.h>
#include <hip/hip_bf16.h>
#include <math.h>

// Problem constants (from reference)
#define BB     8
#define HH     240
#define WW     320
#define HWSZ   (HH * WW)          // 76800
#define NTOT   (BB * HWSZ)        // 614400
#define NBINS  81
#define NBINS1 82                 // bins + pad
#define EPS_SILOG 1e-10f

// Workspace layout (float indices)
#define WS_MAXT   0               // masked max(target), float bits via atomicMax(int)
#define WS_MAXB   1               // max(bin_edges)
#define WS_MODE   2               // mask dtype mode (int): 0=byte, 1=int32, 2=float
#define PART1_OFF 4               // kernel1 partials: [512][4] = sum_d, sum_d2, sum_sq, cnt
#define NBLK1     512
#define MIN_OFF   (PART1_OFF + NBLK1 * 4)     // 2052: per-(b,bin) min array [8*82=656]
#define PA_OFF    (MIN_OFF + BB * NBINS1)     // 2708: kernel2 per-block sum_a partials [512]
#define NBLK2     64                          // chamfer blocks per batch
#define WS_END    (PA_OFF + BB * NBLK2)       // 3220

// ---------------------------------------------------------------------------
__global__ void k_init(float* ws, const unsigned int* mask_words) {
    int tid = threadIdx.x;
    for (int i = tid; i < WS_END; i += blockDim.x) ws[i] = 0.0f;
    __syncthreads();
    for (int i = tid; i < BB * NBINS1; i += blockDim.x) ws[MIN_OFF + i] = INFINITY;
    if (tid == 0) {
        // Probe mask dtype from first 64 words (256 bytes; in-bounds for all modes).
        bool isi = true, isf = true;
        for (int k = 0; k < 64; ++k) {
            unsigned v = mask_words[k];
            if (v != 0u && v != 1u) isi = false;
            if (v != 0u && v != 0x3F800000u) isf = false;
        }
        ((int*)ws)[WS_MODE] = isi ? 1 : (isf ? 2 : 0);
    }
}

__device__ __forceinline__ bool read_mask(const void* mask, int i, int mode) {
    if (mode == 1) return ((const int*)mask)[i] != 0;
    if (mode == 2) return ((const float*)mask)[i] != 0.0f;
    return ((const unsigned char*)mask)[i] != 0;
}

__device__ __forceinline__ float block_reduce_sum(float v, float* red) {
    int tid = threadIdx.x;
    red[tid] = v;
    __syncthreads();
    for (int s = blockDim.x >> 1; s > 0; s >>= 1) {
        if (tid < s) red[tid] += red[tid + s];
        __syncthreads();
    }
    float r = red[0];
    __syncthreads();
    return r;
}

// ---------------------------------------------------------------------------
// Kernel 1: masked sums for silog/l2 + global maxes for pad_value.
__global__ __launch_bounds__(256) void k_stats(const float* __restrict__ pred,
                                               const float* __restrict__ tgt,
                                               const float* __restrict__ bins,
                                               const void*  __restrict__ mask,
                                               float* ws) {
    __shared__ float red[256];
    int mode = ((const int*)ws)[WS_MODE];
    int tid = threadIdx.x;
    int gid = blockIdx.x * blockDim.x + tid;
    int stride = gridDim.x * blockDim.x;

    float sd = 0.f, sd2 = 0.f, ssq = 0.f, cnt = 0.f, mt = 0.f;
    for (int i = gid; i < NTOT; i += stride) {
        float p = pred[i], t = tgt[i];
        if (read_mask(mask, i, mode)) {
            float d = logf(p + EPS_SILOG) - logf(t + EPS_SILOG);
            sd += d; sd2 += d * d;
            float e = p - t; ssq += e * e;
            cnt += 1.0f;
            mt = fmaxf(mt, t);
        }
    }
    if (gid < BB * NBINS) atomicMax((int*)&ws[WS_MAXB], __float_as_int(bins[gid]));

    float b0 = block_reduce_sum(sd, red);
    float b1 = block_reduce_sum(sd2, red);
    float b2 = block_reduce_sum(ssq, red);
    float b3 = block_reduce_sum(cnt, red);
    // max reduce
    red[tid] = mt;
    __syncthreads();
    for (int s = blockDim.x >> 1; s > 0; s >>= 1) {
        if (tid < s) red[tid] = fmaxf(red[tid], red[tid + s]);
        __syncthreads();
    }
    if (tid == 0) {
        float* p4 = &ws[PART1_OFF + blockIdx.x * 4];
        p4[0] = b0; p4[1] = b1; p4[2] = b2; p4[3] = b3;
        atomicMax((int*)&ws[WS_MAXT], __float_as_int(red[0]));
    }
}

// ---------------------------------------------------------------------------
// Kernel 2: fused bidirectional chamfer for one (batch, chunk).
//   Direction A (target->bins): per-thread min over 82 LDS bins, summed.
//   Direction B (bins->target): 3 threads per bin scan 256-target LDS tile.
__global__ __launch_bounds__(256) void k_chamfer(const float* __restrict__ tgt,
                                                 const float* __restrict__ bins,
                                                 const void*  __restrict__ mask,
                                                 float* ws) {
    __shared__ float bins_s[NBINS1];
    __shared__ float tile[256];
    __shared__ float red[256];

    int tid = threadIdx.x;
    int b = blockIdx.x / NBLK2;
    int c = blockIdx.x % NBLK2;
    int mode = ((const int*)ws)[WS_MODE];

    float maxT = ws[WS_MAXT], maxB = ws[WS_MAXB];
    float mx = fmaxf(maxT, maxB), mn = fminf(maxT, maxB);
    float pad = mx + (mx - mn) + 1.0f;

    if (tid < NBINS) bins_s[tid] = bins[b * NBINS + tid];
    if (tid == NBINS) bins_s[NBINS] = pad;
    __syncthreads();

    // Phase-B setup: 3 sub-scanners per bin (246 active lanes).
    float bv = (tid < 246) ? bins_s[tid / 3] : 0.f;
    int   sub = tid % 3;
    float pm = INFINITY;

    float sum_a = 0.f;
    const float* tb = tgt + b * HWSZ;

    for (int base = c * 256; base < HWSZ; base += NBLK2 * 256) {
        int i = base + tid;                       // HWSZ % 256 == 0, always in range
        float t = tb[i];
        bool m = read_mask(mask, b * HWSZ + i, mode);
        float mt = m ? t : pad;
        tile[tid] = mt;

        // Direction A: min over 82 bins (two accumulators to break fmin chain)
        float mv0 = INFINITY, mv1 = INFINITY;
#pragma unroll
        for (int j = 0; j < NBINS1; j += 2) {
            float d0 = mt - bins_s[j];
            float d1 = mt - bins_s[j + 1];
            mv0 = fminf(mv0, d0 * d0);
            mv1 = fminf(mv1, d1 * d1);
        }
        sum_a += fminf(mv0, mv1);
        __syncthreads();

        // Direction B: each of 246 lanes scans 1/3 of the tile for its bin
        if (tid < 246) {
            float p0 = INFINITY, p1 = INFINITY;
            int j = sub;
            for (; j + 3 < 256; j += 6) {
                float d0 = bv - tile[j];
                float d1 = bv - tile[j + 3];
                p0 = fminf(p0, d0 * d0);
                p1 = fminf(p1, d1 * d1);
            }
            for (; j < 256; j += 3) {
                float d = bv - tile[j];
                p0 = fminf(p0, d * d);
            }
            pm = fminf(pm, fminf(p0, p1));
        }
        __syncthreads();
    }

    // Reduce direction-A sum over the block -> deterministic partial.
    float bsum = block_reduce_sum(sum_a, red);
    if (tid == 0) ws[PA_OFF + blockIdx.x] = bsum;

    // Combine the 3 sub-mins per bin, then global atomicMin (order-independent).
    red[tid] = (tid < 246) ? pm : INFINITY;
    __syncthreads();
    if (tid < NBINS1) {
        float m3 = fminf(fminf(red[3 * tid], red[3 * tid + 1]), red[3 * tid + 2]);
        atomicMin((int*)&ws[MIN_OFF + b * NBINS1 + tid], __float_as_int(m3));
    }
}

// ---------------------------------------------------------------------------
// Kernel 3: finalize — fold partials, compute silog + l2 + chamfer.
__global__ __launch_bounds__(256) void k_final(const float* __restrict__ ws, float* out) {
    __shared__ float red[256];
    int tid = threadIdx.x;

    float s0 = 0.f, s1 = 0.f, s2 = 0.f, s3 = 0.f, sa = 0.f, sb = 0.f;
    for (int blk = tid; blk < NBLK1; blk += blockDim.x) {
        const float* p4 = &ws[PART1_OFF + blk * 4];
        s0 += p4[0]; s1 += p4[1]; s2 += p4[2]; s3 += p4[3];
    }
    for (int i = tid; i < BB * NBLK2; i += blockDim.x) sa += ws[PA_OFF + i];
    for (int i = tid; i < BB * NBINS1; i += blockDim.x) sb += ws[MIN_OFF + i];

    s0 = block_reduce_sum(s0, red);
    s1 = block_reduce_sum(s1, red);
    s2 = block_reduce_sum(s2, red);
    s3 = block_reduce_sum(s3, red);
    sa = block_reduce_sum(sa, red);
    sb = block_reduce_sum(sb, red);

    if (tid == 0) {
        float cnt = s3;
        float m1 = s0 / cnt;
        float m2 = s1 / cnt;
        float silog = 10.0f * sqrtf(fmaxf(m2 - 0.85f * m1 * m1, 0.0f));
        float l2 = sqrtf(s2 / cnt);
        float chamfer = (sa + sb) / (float)BB;
        out[0] = l2 + silog + chamfer;
    }
}

// ---------------------------------------------------------------------------
extern "C" void kernel_launch(void* const* d_in, const int* in_sizes, int n_in,
                              void* d_out, int out_size, void* d_ws, size_t ws_size,
                              hipStream_t stream) {
    const float* pred = (const float*)d_in[0];
    const float* tgt  = (const float*)d_in[1];
    const float* bins = (const float*)d_in[2];
    const void*  mask = d_in[3];
    float* ws  = (float*)d_ws;
    float* out = (float*)d_out;

    k_init<<<1, 1024, 0, stream>>>(ws, (const unsigned int*)mask);
    k_stats<<<NBLK1, 256, 0, stream>>>(pred, tgt, bins, mask, ws);
    k_chamfer<<<BB * NBLK2, 256, 0, stream>>>(tgt, bins, mask, ws);
    k_final<<<1, 256, 0, stream>>>(ws, out);
}

// Round 2
// 42.081 us; speedup vs baseline: 1.1997x; 1.1997x over previous
//
#include <hip/hip_runtime.h>
#include <math.h>

// Problem constants
#define BB   8
#define NB   81           // real bins per batch
#define NB1  82           // + pad bin
#define HW   76800
#define NTOT (BB * HW)
#define EPS  1e-10f

#define K1_BLOCKS 128
#define K2_PERB   64
#define K2_BLOCKS (BB * K2_PERB)   // 512

// Workspace layout (float/int indices into ws)
#define WS_MODE   0                        // mask dtype: 0=byte 1=int32 2=float
#define SB_OFF    8                        // sorted bins [8][81]
#define MAXT_OFF  (SB_OFF + BB * NB)       // 656: K1 per-block masked max(target) [128]
#define P2_OFF    (MAXT_OFF + K1_BLOCKS)   // 784: K2 partials [512][5] sd,sd2,ssq,cnt,sumA
#define A_OFF     (P2_OFF + K2_BLOCKS * 5) // 3344: Acand bits [8][83] (max target per slot)
#define B_OFF     (A_OFF + BB * 83)        // 4008: Bcand bits [8][83] (min target per slot)
#define WS_END    (B_OFF + BB * 83)        // 4672

__device__ __forceinline__ int probe_mode(const void* mask) {
    const unsigned* mw = (const unsigned*)mask;
    bool isi = true, isf = true;
    for (int k = 0; k < 64; ++k) {
        unsigned v = mw[k];
        if (v != 0u && v != 1u) isi = false;
        if (v != 0u && v != 0x3F800000u) isf = false;
    }
    return isi ? 1 : (isf ? 2 : 0);
}

__device__ __forceinline__ bool read_mask(const void* mask, int i, int mode) {
    if (mode == 1) return ((const int*)mask)[i] != 0;
    if (mode == 2) return ((const float*)mask)[i] != 0.0f;
    return ((const unsigned char*)mask)[i] != 0;
}

// blockDim.x == 256 assumed for both helpers (deterministic tree reduce)
__device__ __forceinline__ float bsum(float v, float* red) {
    int tid = threadIdx.x;
    red[tid] = v; __syncthreads();
    for (int s = 128; s > 0; s >>= 1) { if (tid < s) red[tid] += red[tid + s]; __syncthreads(); }
    float r = red[0]; __syncthreads();
    return r;
}
__device__ __forceinline__ float bmax(float v, float* red) {
    int tid = threadIdx.x;
    red[tid] = v; __syncthreads();
    for (int s = 128; s > 0; s >>= 1) { if (tid < s) red[tid] = fmaxf(red[tid], red[tid + s]); __syncthreads(); }
    float r = red[0]; __syncthreads();
    return r;
}

// ---------------------------------------------------------------------------
// K1: mask-mode probe + masked max(target) partials + per-batch bin sort +
//     sentinel init of the A/B candidate arrays. All plain stores (no init deps).
__global__ __launch_bounds__(256) void k_prep(const float* __restrict__ tgt,
                                              const float* __restrict__ bins,
                                              const void*  __restrict__ mask,
                                              float* ws) {
    __shared__ int   s_mode;
    __shared__ float sbin[NB];
    __shared__ float red[4];
    int tid = threadIdx.x, bid = blockIdx.x;

    if (tid == 0) {
        s_mode = probe_mode(mask);
        if (bid == 0) ((int*)ws)[WS_MODE] = s_mode;
    }
    // rank-sort this batch's 81 bins (blocks 0..7)
    if (bid < BB && tid < NB) sbin[tid] = bins[bid * NB + tid];
    __syncthreads();
    int mode = s_mode;
    if (bid < BB && tid < NB) {
        float v = sbin[tid];
        int r = 0;
        for (int k = 0; k < NB; ++k) {
            float u = sbin[k];
            r += (u < v) || (u == v && k < tid);   // stable, exact permutation
        }
        ws[SB_OFF + bid * NB + r] = v;
    }
    // sentinel init for candidate arrays (block 8) — runs before K2's atomics
    if (bid == 8) {
        int* wi = (int*)ws;
        for (int i = tid; i < BB * 83; i += 256) {
            wi[A_OFF + i] = 0xFF800000;   // -inf bits (atomicMax int works: positives win)
            wi[B_OFF + i] = 0x7F800000;   // +inf bits
        }
    }

    // masked max(target), vectorized x4
    float mt = 0.0f;
    const int n4 = NTOT / 4;
    for (int i = bid * 256 + tid; i < n4; i += K1_BLOCKS * 256) {
        float4 t4 = ((const float4*)tgt)[i];
        int m0, m1, m2, m3;
        if (mode == 0) {
            unsigned um = ((const unsigned*)mask)[i];
            m0 = um & 0xFF; m1 = (um >> 8) & 0xFF; m2 = (um >> 16) & 0xFF; m3 = (um >> 24) & 0xFF;
        } else if (mode == 1) {
            uint4 u4 = ((const uint4*)mask)[i];
            m0 = u4.x; m1 = u4.y; m2 = u4.z; m3 = u4.w;
        } else {
            float4 f4 = ((const float4*)mask)[i];
            m0 = f4.x != 0.f; m1 = f4.y != 0.f; m2 = f4.z != 0.f; m3 = f4.w != 0.f;
        }
        if (m0) mt = fmaxf(mt, t4.x);
        if (m1) mt = fmaxf(mt, t4.y);
        if (m2) mt = fmaxf(mt, t4.z);
        if (m3) mt = fmaxf(mt, t4.w);
    }
    for (int o = 32; o > 0; o >>= 1) mt = fmaxf(mt, __shfl_down(mt, o, 64));
    if ((tid & 63) == 0) red[tid >> 6] = mt;
    __syncthreads();
    if (tid == 0)
        ws[MAXT_OFF + bid] = fmaxf(fmaxf(red[0], red[1]), fmaxf(red[2], red[3]));
}

// ---------------------------------------------------------------------------
// K2: single pass over all pixels. Per element: silog/l2 stats + chamfer via
// sorted-bin slot counting (dir A exact from flanking bins; dir B via per-slot
// max/min target candidates, merged with order-independent int atomics).
__global__ __launch_bounds__(256) void k_main(const float* __restrict__ pred,
                                              const float* __restrict__ tgt,
                                              const void*  __restrict__ mask,
                                              float* ws) {
    __shared__ float ss[84];           // [-inf, s_0..s_80, pad, +inf]
    __shared__ int   iA[83], iB[83];   // per-slot candidate bits
    __shared__ float red[256];
    __shared__ float s_pad;

    int tid = threadIdx.x;
    int b = blockIdx.x >> 6, c = blockIdx.x & 63;
    int mode = ((const int*)ws)[WS_MODE];

    // global maxT (128 partials) and maxB (8 sorted-bin tops) -> pad
    float maxT = bmax(tid < K1_BLOCKS ? ws[MAXT_OFF + tid] : -INFINITY, red);
    float maxB = bmax(tid < BB ? ws[SB_OFF + tid * NB + (NB - 1)] : -INFINITY, red);
    if (tid == 0) {
        float mx = fmaxf(maxT, maxB), mn = fminf(maxT, maxB);
        float pad = mx + (mx - mn) + 1.0f;
        s_pad = pad;
        ss[0] = -INFINITY; ss[NB1] = pad; ss[NB1 + 1] = INFINITY;
    }
    if (tid < NB)  ss[1 + tid] = ws[SB_OFF + b * NB + tid];
    if (tid < 83) { iA[tid] = 0xFF800000; iB[tid] = 0x7F800000; }
    __syncthreads();

    float pad = s_pad;
    float sd = 0.f, sd2 = 0.f, ssq = 0.f, cnt = 0.f, dA = 0.f;
    const float* tb = tgt + b * HW;
    const float* pb = pred + b * HW;

    for (int i = c * 256 + tid; i < HW; i += K2_PERB * 256) {
        float t = tb[i], p = pb[i];
        bool m = read_mask(mask, b * HW + i, mode);
        float mt2;
        if (m) {
            float d = logf((p + EPS) / (t + EPS));
            sd += d; sd2 += d * d;
            float e = p - t; ssq += e * e;
            cnt += 1.0f;
            mt2 = t;
        } else mt2 = pad;

        // slot = #sorted-mod-bins <= mt2  (82 cheap broadcast-LDS compares)
        int c82 = 0;
#pragma unroll
        for (int k = 1; k <= NB1; ++k) c82 += (ss[k] <= mt2) ? 1 : 0;

        // direction A: exact nearest-bin distance from the two flanks
        float lo = ss[c82], hi = ss[c82 + 1];
        float dl = mt2 - lo, dh = hi - mt2;
        dA += fminf(dl * dl, dh * dh);

        // direction B candidates: max/min target in this slot
        int bits = __float_as_int(mt2);
        atomicMax(&iA[c82], bits);
        atomicMin(&iB[c82], bits);
    }

    // partials (plain stores, fixed-order reduce -> deterministic)
    float r0 = bsum(sd, red);
    float r1 = bsum(sd2, red);
    float r2 = bsum(ssq, red);
    float r3 = bsum(cnt, red);
    float r4 = bsum(dA, red);
    if (tid == 0) {
        float* p5 = &ws[P2_OFF + blockIdx.x * 5];
        p5[0] = r0; p5[1] = r1; p5[2] = r2; p5[3] = r3; p5[4] = r4;
    }
    __syncthreads();
    if (tid < 83) {
        atomicMax((int*)ws + A_OFF + b * 83 + tid, iA[tid]);
        atomicMin((int*)ws + B_OFF + b * 83 + tid, iB[tid]);
    }
}

// ---------------------------------------------------------------------------
// K3: fold partials; per-batch 82-step prefix/suffix sweep turns slot
// candidates into exact direction-B distances; combine all three losses.
__global__ __launch_bounds__(256) void k_final(const float* __restrict__ ws, float* out) {
    __shared__ float tmpR[BB][NB1];
    __shared__ float red[256];
    __shared__ float sums8[BB];
    __shared__ float s_pad;
    int tid = threadIdx.x;

    float s0 = 0.f, s1 = 0.f, s2 = 0.f, s3 = 0.f, sa = 0.f;
    for (int i = tid; i < K2_BLOCKS; i += 256) {
        const float* p5 = &ws[P2_OFF + i * 5];
        s0 += p5[0]; s1 += p5[1]; s2 += p5[2]; s3 += p5[3]; sa += p5[4];
    }
    s0 = bsum(s0, red); s1 = bsum(s1, red); s2 = bsum(s2, red);
    s3 = bsum(s3, red); sa = bsum(sa, red);

    float maxT = bmax(tid < K1_BLOCKS ? ws[MAXT_OFF + tid] : -INFINITY, red);
    float maxB = bmax(tid < BB ? ws[SB_OFF + tid * NB + (NB - 1)] : -INFINITY, red);
    if (tid == 0) {
        float mx = fmaxf(maxT, maxB), mn = fminf(maxT, maxB);
        s_pad = mx + (mx - mn) + 1.0f;
    }
    __syncthreads();
    float pad = s_pad;

    if (tid < BB) {
        const int* Ac = (const int*)ws + A_OFF + tid * 83;
        const int* Bc = (const int*)ws + B_OFF + tid * 83;
        // backward: R[k] = min target in slots >= k+1
        float rmin = INFINITY;
        for (int k = NB1 - 1; k >= 0; --k) {
            rmin = fminf(rmin, __int_as_float(Bc[k + 1]));
            float sk = (k < NB) ? ws[SB_OFF + tid * NB + k] : pad;
            float d = rmin - sk;
            tmpR[tid][k] = d * d;            // +inf flows through harmlessly
        }
        // forward: L[k] = max target in slots <= k; combine
        float lmax = -INFINITY, sb = 0.f;
        for (int k = 0; k < NB1; ++k) {
            lmax = fmaxf(lmax, __int_as_float(Ac[k]));
            float sk = (k < NB) ? ws[SB_OFF + tid * NB + k] : pad;
            float d = sk - lmax;
            sb += fminf(d * d, tmpR[tid][k]);
        }
        sums8[tid] = sb;
    }
    __syncthreads();

    if (tid == 0) {
        float sumB = 0.f;
        for (int i = 0; i < BB; ++i) sumB += sums8[i];
        float cntv = s3;
        float m1 = s0 / cntv, m2 = s1 / cntv;
        float silog = 10.0f * sqrtf(fmaxf(m2 - 0.85f * m1 * m1, 0.0f));
        float l2 = sqrtf(s2 / cntv);
        float chamfer = (sa + sumB) / (float)BB;
        out[0] = l2 + silog + chamfer;
    }
}

// ---------------------------------------------------------------------------
extern "C" void kernel_launch(void* const* d_in, const int* in_sizes, int n_in,
                              void* d_out, int out_size, void* d_ws, size_t ws_size,
                              hipStream_t stream) {
    const float* pred = (const float*)d_in[0];
    const float* tgt  = (const float*)d_in[1];
    const float* bins = (const float*)d_in[2];
    const void*  mask = d_in[3];
    float* ws  = (float*)d_ws;
    float* out = (float*)d_out;

    k_prep<<<K1_BLOCKS, 256, 0, stream>>>(tgt, bins, mask, ws);
    k_main<<<K2_BLOCKS, 256, 0, stream>>>(pred, tgt, mask, ws);
    k_final<<<1, 256, 0, stream>>>(ws, out);
}